// Round 6
// baseline (178.404 us; speedup 1.0000x reference)
//
#include <hip/hip_runtime.h>
#include <hip/hip_bf16.h>

// Causal attention head. B=8, T=4096, D_EMBED=128, HEAD=64. f32 wire, bf16 MFMA.
typedef __attribute__((ext_vector_type(8))) short bf16x8;
typedef __attribute__((ext_vector_type(4))) short short4v;
typedef __attribute__((ext_vector_type(4))) float f32x4;

#define MFMA16(a, b, c) __builtin_amdgcn_mfma_f32_16x16x32_bf16((a), (b), (c), 0, 0, 0)

constexpr int Bn = 8, Tn = 4096, Dn = 128, Hn = 64;

__device__ inline unsigned short f2b(float f) {
    union { float f; unsigned u; } v; v.f = f;
    unsigned r = v.u + 0x7fff + ((v.u >> 16) & 1);   // RNE, inputs finite
    return (unsigned short)(r >> 16);
}

// ---- Kernel 0: transpose three [128][64] f32 weights into bf16 WT[3][64][128] ----
__global__ void wtrans(const float* __restrict__ Wq,
                       const float* __restrict__ Wk,
                       const float* __restrict__ Wv,
                       unsigned short* __restrict__ WT) {
    int m = blockIdx.x;
    const float* W = (m == 0) ? Wq : (m == 1) ? Wk : Wv;
    unsigned short* o = WT + m * Hn * Dn;
    for (int i = threadIdx.x; i < Hn * Dn; i += blockDim.x) {
        int n = i >> 7, k = i & 127;
        o[i] = f2b(W[k * Hn + n]);
    }
}

// ---- Kernel 1: QKV projection, coalesced I/O via LDS tiles. ----
// Q (pre-scaled by log2(e)/sqrt(128)), K: bf16 [B*T][64]. V: bf16 VT[B][64][T].
__global__ __launch_bounds__(256) void qkv(const float* __restrict__ X,
                                           const unsigned short* __restrict__ WT,
                                           unsigned short* __restrict__ Qp,
                                           unsigned short* __restrict__ Kp,
                                           unsigned short* __restrict__ VTp) {
    __shared__ unsigned short xt[64 * 136];
    __shared__ unsigned short ot[64 * 72];
    int tid = threadIdx.x, w = tid >> 6, lane = tid & 63, quad = lane >> 4, l15 = lane & 15;
    int m0 = blockIdx.x * 64;
    int b = m0 >> 12, tloc = m0 & (Tn - 1);
    const float kLog2Scale = 0.12751879523175464f;  // (1/sqrt(128)) * log2(e)

    #pragma unroll
    for (int c = 0; c < 8; c++) {
        int e = tid * 4 + c * 1024;
        int row = e >> 7, col = e & 127;
        f32x4 v = *(const f32x4*)&X[(size_t)(m0 + row) * Dn + col];
        short4v s4;
        s4[0] = (short)f2b(v[0]); s4[1] = (short)f2b(v[1]);
        s4[2] = (short)f2b(v[2]); s4[3] = (short)f2b(v[3]);
        *(short4v*)&xt[row * 136 + col] = s4;
    }
    __syncthreads();

    bf16x8 a[4];
    #pragma unroll
    for (int kt = 0; kt < 4; kt++)
        a[kt] = *(const bf16x8*)&xt[(w * 16 + l15) * 136 + kt * 32 + quad * 8];

    for (int mat = 0; mat < 3; mat++) {
        f32x4 acc[4];
        #pragma unroll
        for (int nt = 0; nt < 4; nt++) {
            acc[nt] = (f32x4){0.f, 0.f, 0.f, 0.f};
            const unsigned short* wtm = WT + mat * Hn * Dn + (size_t)(nt * 16 + l15) * Dn + quad * 8;
            #pragma unroll
            for (int kt = 0; kt < 4; kt++)
                acc[nt] = MFMA16(a[kt], *(const bf16x8*)&wtm[kt * 32], acc[nt]);
        }
        __syncthreads();
        if (mat < 2) {
            float sc = (mat == 0) ? kLog2Scale : 1.0f;   // fold softmax scale into Q
            #pragma unroll
            for (int nt = 0; nt < 4; nt++)
                #pragma unroll
                for (int rg = 0; rg < 4; rg++)
                    ot[(w * 16 + quad * 4 + rg) * 72 + nt * 16 + l15] = f2b(acc[nt][rg] * sc);
        } else {
            #pragma unroll
            for (int nt = 0; nt < 4; nt++) {
                short4v pk;
                pk[0] = (short)f2b(acc[nt][0]); pk[1] = (short)f2b(acc[nt][1]);
                pk[2] = (short)f2b(acc[nt][2]); pk[3] = (short)f2b(acc[nt][3]);
                *(short4v*)&ot[(nt * 16 + l15) * 72 + w * 16 + quad * 4] = pk;
            }
        }
        __syncthreads();
        if (mat < 2) {
            unsigned short* O = mat ? Kp : Qp;
            #pragma unroll
            for (int i = 0; i < 2; i++) {
                int row = (tid >> 3) + 32 * i, ch = tid & 7;
                *(bf16x8*)&O[(size_t)(m0 + row) * Hn + ch * 8] = *(const bf16x8*)&ot[row * 72 + ch * 8];
            }
        } else {
            #pragma unroll
            for (int i = 0; i < 2; i++) {
                int h = (tid >> 3) + 32 * i, ch = tid & 7;
                *(bf16x8*)&VTp[((size_t)(b * Hn + h)) * Tn + tloc + ch * 8] = *(const bf16x8*)&ot[h * 72 + ch * 8];
            }
        }
    }
}

// ---- Kernel 2: flash attention with k-split. Each block: (b, qt, chunk of <=16
// k-tiles). Partials (unnormalized O, li) atomically accumulated in f32. ----
__global__ __launch_bounds__(256) void attn(const unsigned short* __restrict__ Qp,
                                            const unsigned short* __restrict__ Kp,
                                            const unsigned short* __restrict__ VTp,
                                            float* __restrict__ OutAcc,
                                            float* __restrict__ Lsum) {
    __shared__ unsigned short Ps[4][32 * 40];   // per-wave P buffer [q 32][k' 32]
    __shared__ float Cbuf[2][32][66];
    __shared__ float Lbuf[2][64];

    int idx = blockIdx.x;
    int b = idx & 7;                            // b -> XCD -> K/V L2-local
    int c = 159 - (idx >> 3);                   // big chunks (c high) dispatch first
    int qt, ch;
    if (c < 16)      { qt = c;                ch = 0; }
    else if (c < 48) { int t = c - 16; qt = 16 + (t >> 1); ch = t & 1; }
    else if (c < 96) { int t = c - 48; int q3 = t / 3; qt = 32 + q3; ch = t - 3 * q3; }
    else             { int t = c - 96; qt = 48 + (t >> 2); ch = t & 3; }
    int k0 = ch * 16;
    int k1 = min(qt, k0 + 15);

    int tid = threadIdx.x, w = tid >> 6, lane = tid & 63, quad = lane >> 4, l15 = lane & 15;
    int qh = w & 1, kh = w >> 1;

    int Q0 = qt * 64;
    const unsigned short* Kb = Kp + (size_t)b * Tn * Hn;
    const unsigned short* Vb = VTp + (size_t)b * Hn * Tn;

    f32x4 o[2][4];
    #pragma unroll
    for (int nq = 0; nq < 2; nq++)
        #pragma unroll
        for (int nh = 0; nh < 4; nh++) o[nq][nh] = (f32x4){0.f, 0.f, 0.f, 0.f};
    float li[2] = {0.f, 0.f};
    unsigned short* Pw = &Ps[w][0];

    // K/V register double-buffer (tile k0 first)
    bf16x8 kf0[2][2], vf0[4], kf1[2][2], vf1[4];
    {
        int kk = k0 * 64 + kh * 32;
        #pragma unroll
        for (int mt = 0; mt < 2; mt++)
            #pragma unroll
            for (int hc = 0; hc < 2; hc++)
                kf0[mt][hc] = *(const bf16x8*)&Kb[(size_t)(kk + mt * 16 + l15) * Hn + hc * 32 + quad * 8];
        #pragma unroll
        for (int nh = 0; nh < 4; nh++)
            vf0[nh] = *(const bf16x8*)&Vb[(size_t)(nh * 16 + l15) * Tn + kk + quad * 8];
    }
    // Q B-frags (pre-scaled at projection)
    bf16x8 qf[2][2];
    {
        const unsigned short* Qb = Qp + ((size_t)b * Tn + Q0 + qh * 32) * Hn;
        #pragma unroll
        for (int nq = 0; nq < 2; nq++)
            #pragma unroll
            for (int hc = 0; hc < 2; hc++)
                qf[nq][hc] = *(const bf16x8*)&Qb[(nq * 16 + l15) * Hn + hc * 32 + quad * 8];
    }

    auto body = [&](bf16x8 (&kc)[2][2], bf16x8 (&vc)[4],
                    bf16x8 (&kn)[2][2], bf16x8 (&vn)[4], int kt) {
        if (kt < k1) {
            int kk2 = (kt + 1) * 64 + kh * 32;
            #pragma unroll
            for (int mt = 0; mt < 2; mt++)
                #pragma unroll
                for (int hc = 0; hc < 2; hc++)
                    kn[mt][hc] = *(const bf16x8*)&Kb[(size_t)(kk2 + mt * 16 + l15) * Hn + hc * 32 + quad * 8];
            #pragma unroll
            for (int nh = 0; nh < 4; nh++)
                vn[nh] = *(const bf16x8*)&Vb[(size_t)(nh * 16 + l15) * Tn + kk2 + quad * 8];
        }
        int kk = kt * 64 + kh * 32;
        f32x4 s[2][2];
        #pragma unroll
        for (int mt = 0; mt < 2; mt++)
            #pragma unroll
            for (int nq = 0; nq < 2; nq++) {
                f32x4 acc = {0.f, 0.f, 0.f, 0.f};
                acc = MFMA16(kc[mt][0], qf[nq][0], acc);
                acc = MFMA16(kc[mt][1], qf[nq][1], acc);
                s[mt][nq] = acc;
            }
        bool diag = (kt == qt);
        int kbase = kk + quad * 4;
        int qbase = Q0 + qh * 32 + l15;
        #pragma unroll
        for (int mt = 0; mt < 2; mt++) {
            #pragma unroll
            for (int nq = 0; nq < 2; nq++) {
                short4v pk;
                #pragma unroll
                for (int rg = 0; rg < 4; rg++) {
                    float p = __builtin_amdgcn_exp2f(s[mt][nq][rg]);
                    if (diag && (kbase + mt * 16 + rg > qbase + nq * 16)) p = 0.f;
                    li[nq] += p;
                    pk[rg] = (short)f2b(p);
                }
                *(short4v*)&Pw[(nq * 16 + l15) * 40 + mt * 16 + quad * 4] = pk;
            }
        }
        bf16x8 pf[2];
        #pragma unroll
        for (int nq = 0; nq < 2; nq++)
            pf[nq] = *(const bf16x8*)&Pw[(nq * 16 + l15) * 40 + quad * 8];
        #pragma unroll
        for (int nq = 0; nq < 2; nq++)
            #pragma unroll
            for (int nh = 0; nh < 4; nh++)
                o[nq][nh] = MFMA16(pf[nq], vc[nh], o[nq][nh]);
    };

    int kt = k0;
    for (;;) {
        body(kf0, vf0, kf1, vf1, kt);
        if (++kt > k1) break;
        body(kf1, vf1, kf0, vf0, kt);
        if (++kt > k1) break;
    }

    // ---- epilogue: combine kh pair in LDS, then atomic-accumulate ----
    __syncthreads();
    #pragma unroll
    for (int nq = 0; nq < 2; nq++) {
        li[nq] += __shfl_xor(li[nq], 16);
        li[nq] += __shfl_xor(li[nq], 32);
    }
    if (lane < 16) {
        Lbuf[kh][qh * 32 + lane]      = li[0];
        Lbuf[kh][qh * 32 + 16 + lane] = li[1];
    }
    if (kh == 1) {
        #pragma unroll
        for (int nq = 0; nq < 2; nq++)
            #pragma unroll
            for (int nh = 0; nh < 4; nh++)
                #pragma unroll
                for (int rg = 0; rg < 4; rg++)
                    Cbuf[qh][nq * 16 + quad * 4 + rg][nh * 16 + l15] = o[nq][nh][rg];
    }
    __syncthreads();
    if (kh == 0) {
        #pragma unroll
        for (int nq = 0; nq < 2; nq++) {
            #pragma unroll
            for (int rg = 0; rg < 4; rg++) {
                int qloc = nq * 16 + quad * 4 + rg;
                size_t row = (size_t)b * Tn + Q0 + qh * 32 + qloc;
                #pragma unroll
                for (int nh = 0; nh < 4; nh++)
                    atomicAdd(&OutAcc[row * Hn + nh * 16 + l15],
                              o[nq][nh][rg] + Cbuf[qh][qloc][nh * 16 + l15]);
            }
        }
    }
    if (w == 0)   // 64 lanes: one q-row each
        atomicAdd(&Lsum[(size_t)b * Tn + Q0 + lane], Lbuf[0][lane] + Lbuf[1][lane]);
}

// ---- Kernel 3: normalize ----
__global__ __launch_bounds__(256) void norm_out(float* __restrict__ Out,
                                                const float* __restrict__ Lsum) {
    int i = (blockIdx.x * 256 + threadIdx.x) * 4;
    f32x4 v = *(const f32x4*)&Out[i];
    float inv = 1.0f / Lsum[i >> 6];
    v[0] *= inv; v[1] *= inv; v[2] *= inv; v[3] *= inv;
    *(f32x4*)&Out[i] = v;
}

extern "C" void kernel_launch(void* const* d_in, const int* in_sizes, int n_in,
                              void* d_out, int out_size, void* d_ws, size_t ws_size,
                              hipStream_t stream) {
    const float* X  = (const float*)d_in[0];
    const float* Wq = (const float*)d_in[1];
    const float* Wk = (const float*)d_in[2];
    const float* Wv = (const float*)d_in[3];
    float* out = (float*)d_out;

    char* ws = (char*)d_ws;
    size_t szQ = (size_t)Bn * Tn * Hn * sizeof(unsigned short);  // 4 MiB
    unsigned short* Qp  = (unsigned short*)(ws);
    unsigned short* Kp  = (unsigned short*)(ws + szQ);
    unsigned short* VTp = (unsigned short*)(ws + 2 * szQ);
    unsigned short* WT  = (unsigned short*)(ws + 3 * szQ);           // + 48 KiB
    float*          Ls  = (float*)(ws + 3 * szQ + 64 * 1024);        // 128 KiB

    hipMemsetAsync(out, 0, (size_t)out_size * sizeof(float), stream);
    hipMemsetAsync(Ls, 0, (size_t)Bn * Tn * sizeof(float), stream);
    wtrans<<<3, 256, 0, stream>>>(Wq, Wk, Wv, WT);
    qkv<<<Bn * Tn / 64, 256, 0, stream>>>(X, WT, Qp, Kp, VTp);
    attn<<<1280, 256, 0, stream>>>(Qp, Kp, VTp, out, Ls);
    norm_out<<<(Bn * Tn * Hn / 4) / 256, 256, 0, stream>>>(out, Ls);
}

// Round 7
// 150.801 us; speedup vs baseline: 1.1830x; 1.1830x over previous
//
#include <hip/hip_runtime.h>
#include <hip/hip_bf16.h>

// Causal attention head. B=8, T=4096, D_EMBED=128, HEAD=64. f32 wire, bf16 MFMA.
typedef __attribute__((ext_vector_type(8))) short bf16x8;
typedef __attribute__((ext_vector_type(4))) short short4v;
typedef __attribute__((ext_vector_type(4))) float f32x4;

#define MFMA16(a, b, c) __builtin_amdgcn_mfma_f32_16x16x32_bf16((a), (b), (c), 0, 0, 0)

constexpr int Bn = 8, Tn = 4096, Dn = 128, Hn = 64;

__device__ inline unsigned short f2b(float f) {
    union { float f; unsigned u; } v; v.f = f;
    unsigned r = v.u + 0x7fff + ((v.u >> 16) & 1);   // RNE, inputs finite
    return (unsigned short)(r >> 16);
}

// ---- Kernel 0: transpose three [128][64] f32 weights into bf16 WT[3][64][128] ----
__global__ void wtrans(const float* __restrict__ Wq,
                       const float* __restrict__ Wk,
                       const float* __restrict__ Wv,
                       unsigned short* __restrict__ WT) {
    int m = blockIdx.x;
    const float* W = (m == 0) ? Wq : (m == 1) ? Wk : Wv;
    unsigned short* o = WT + m * Hn * Dn;
    for (int i = threadIdx.x; i < Hn * Dn; i += blockDim.x) {
        int n = i >> 7, k = i & 127;
        o[i] = f2b(W[k * Hn + n]);
    }
}

// ---- Kernel 1: QKV projection, coalesced I/O via LDS tiles. ----
// Q (pre-scaled by log2(e)/sqrt(128)), K: bf16 [B*T][64]. V: bf16 VT[B][64][T].
__global__ __launch_bounds__(256) void qkv(const float* __restrict__ X,
                                           const unsigned short* __restrict__ WT,
                                           unsigned short* __restrict__ Qp,
                                           unsigned short* __restrict__ Kp,
                                           unsigned short* __restrict__ VTp) {
    __shared__ unsigned short xt[64 * 136];
    __shared__ unsigned short ot[64 * 72];
    int tid = threadIdx.x, w = tid >> 6, lane = tid & 63, quad = lane >> 4, l15 = lane & 15;
    int m0 = blockIdx.x * 64;
    int b = m0 >> 12, tloc = m0 & (Tn - 1);
    const float kLog2Scale = 0.12751879523175464f;  // (1/sqrt(128)) * log2(e)

    #pragma unroll
    for (int c = 0; c < 8; c++) {
        int e = tid * 4 + c * 1024;
        int row = e >> 7, col = e & 127;
        f32x4 v = *(const f32x4*)&X[(size_t)(m0 + row) * Dn + col];
        short4v s4;
        s4[0] = (short)f2b(v[0]); s4[1] = (short)f2b(v[1]);
        s4[2] = (short)f2b(v[2]); s4[3] = (short)f2b(v[3]);
        *(short4v*)&xt[row * 136 + col] = s4;
    }
    __syncthreads();

    bf16x8 a[4];
    #pragma unroll
    for (int kt = 0; kt < 4; kt++)
        a[kt] = *(const bf16x8*)&xt[(w * 16 + l15) * 136 + kt * 32 + quad * 8];

    for (int mat = 0; mat < 3; mat++) {
        f32x4 acc[4];
        #pragma unroll
        for (int nt = 0; nt < 4; nt++) {
            acc[nt] = (f32x4){0.f, 0.f, 0.f, 0.f};
            const unsigned short* wtm = WT + mat * Hn * Dn + (size_t)(nt * 16 + l15) * Dn + quad * 8;
            #pragma unroll
            for (int kt = 0; kt < 4; kt++)
                acc[nt] = MFMA16(a[kt], *(const bf16x8*)&wtm[kt * 32], acc[nt]);
        }
        __syncthreads();
        if (mat < 2) {
            float sc = (mat == 0) ? kLog2Scale : 1.0f;   // fold softmax scale into Q
            #pragma unroll
            for (int nt = 0; nt < 4; nt++)
                #pragma unroll
                for (int rg = 0; rg < 4; rg++)
                    ot[(w * 16 + quad * 4 + rg) * 72 + nt * 16 + l15] = f2b(acc[nt][rg] * sc);
        } else {
            #pragma unroll
            for (int nt = 0; nt < 4; nt++) {
                short4v pk;
                pk[0] = (short)f2b(acc[nt][0]); pk[1] = (short)f2b(acc[nt][1]);
                pk[2] = (short)f2b(acc[nt][2]); pk[3] = (short)f2b(acc[nt][3]);
                *(short4v*)&ot[(nt * 16 + l15) * 72 + w * 16 + quad * 4] = pk;
            }
        }
        __syncthreads();
        if (mat < 2) {
            unsigned short* O = mat ? Kp : Qp;
            #pragma unroll
            for (int i = 0; i < 2; i++) {
                int row = (tid >> 3) + 32 * i, ch = tid & 7;
                *(bf16x8*)&O[(size_t)(m0 + row) * Hn + ch * 8] = *(const bf16x8*)&ot[row * 72 + ch * 8];
            }
        } else {
            #pragma unroll
            for (int i = 0; i < 2; i++) {
                int h = (tid >> 3) + 32 * i, ch = tid & 7;
                *(bf16x8*)&VTp[((size_t)(b * Hn + h)) * Tn + tloc + ch * 8] = *(const bf16x8*)&ot[h * 72 + ch * 8];
            }
        }
    }
}

// ---- Kernel 2: flash attention. Block = (b, qt, q-half 32). 128 threads = 2 waves
// (k'-halves). K/V staged via LDS with coalesced loads + register prefetch. ----
__global__ __launch_bounds__(128) void attn(const unsigned short* __restrict__ Qp,
                                            const unsigned short* __restrict__ Kp,
                                            const unsigned short* __restrict__ VTp,
                                            float* __restrict__ Out) {
    __shared__ unsigned short Ks[64 * 72];      // [k'][h]
    __shared__ unsigned short Vs[64 * 72];      // [h][k']
    __shared__ unsigned short Ps[2][32 * 40];   // per-wave P [q 32][k' 32]
    __shared__ float Cbuf[32][66];              // kh=1 -> kh=0 combine
    __shared__ float Lbuf[2][32];

    int idx = blockIdx.x;
    int b = idx & 7;                  // round-robin across XCDs -> K/V L2-local
    int qh = (idx >> 3) & 1;
    int qt = 63 - (idx >> 4);         // heavy q-tiles dispatch first

    int tid = threadIdx.x, w = tid >> 6, lane = tid & 63, quad = lane >> 4, l15 = lane & 15;
    int kh = w;
    int Q0 = qt * 64;
    const unsigned short* Kb = Kp + (size_t)b * Tn * Hn;
    const unsigned short* Vb = VTp + (size_t)b * Hn * Tn;

    // staging geometry: thread covers 4x 16B chunks of each 8 KB tile
    int srow = tid >> 3, scol = (tid & 7) * 8;   // shorts
    const f32x4* Ksrc = (const f32x4*)Kb;        // K tile kt is contiguous: 512 f32x4

    // prologue: prefetch tile 0 into registers (coalesced: 8 lines/instr)
    f32x4 kr[4], vr[4];
    #pragma unroll
    for (int i = 0; i < 4; i++) kr[i] = Ksrc[tid + i * 128];
    #pragma unroll
    for (int i = 0; i < 4; i++) vr[i] = *(const f32x4*)&Vb[(size_t)(srow + i * 16) * Tn + scol];

    // Q B-frags (pre-scaled at projection)
    bf16x8 qf[2][2];
    {
        const unsigned short* Qb = Qp + ((size_t)b * Tn + Q0 + qh * 32) * Hn;
        #pragma unroll
        for (int nq = 0; nq < 2; nq++)
            #pragma unroll
            for (int hc = 0; hc < 2; hc++)
                qf[nq][hc] = *(const bf16x8*)&Qb[(nq * 16 + l15) * Hn + hc * 32 + quad * 8];
    }

    f32x4 o[2][4];
    #pragma unroll
    for (int nq = 0; nq < 2; nq++)
        #pragma unroll
        for (int nh = 0; nh < 4; nh++) o[nq][nh] = (f32x4){0.f, 0.f, 0.f, 0.f};
    float li[2] = {0.f, 0.f};
    unsigned short* Pw = &Ps[w][0];

    for (int kt = 0; kt <= qt; kt++) {
        __syncthreads();   // previous iteration's LDS readers done
        #pragma unroll
        for (int i = 0; i < 4; i++) *(f32x4*)&Ks[(srow + i * 16) * 72 + scol] = kr[i];
        #pragma unroll
        for (int i = 0; i < 4; i++) *(f32x4*)&Vs[(srow + i * 16) * 72 + scol] = vr[i];
        __syncthreads();
        if (kt < qt) {     // prefetch tile kt+1; latency overlaps compute below
            #pragma unroll
            for (int i = 0; i < 4; i++) kr[i] = Ksrc[(kt + 1) * 512 + tid + i * 128];
            #pragma unroll
            for (int i = 0; i < 4; i++)
                vr[i] = *(const f32x4*)&Vb[(size_t)(srow + i * 16) * Tn + (kt + 1) * 64 + scol];
        }

        // K A-frags / V B-frags from LDS
        bf16x8 kf[2][2], vf[4];
        #pragma unroll
        for (int mt = 0; mt < 2; mt++)
            #pragma unroll
            for (int hc = 0; hc < 2; hc++)
                kf[mt][hc] = *(const bf16x8*)&Ks[(kh * 32 + mt * 16 + l15) * 72 + hc * 32 + quad * 8];
        #pragma unroll
        for (int nh = 0; nh < 4; nh++)
            vf[nh] = *(const bf16x8*)&Vs[(nh * 16 + l15) * 72 + kh * 32 + quad * 8];

        // S^T tiles: rows k' = mt*16+quad*4+rg, cols q = nq*16+l15 (log2-scaled)
        f32x4 s[2][2];
        #pragma unroll
        for (int mt = 0; mt < 2; mt++)
            #pragma unroll
            for (int nq = 0; nq < 2; nq++) {
                f32x4 acc = {0.f, 0.f, 0.f, 0.f};
                acc = MFMA16(kf[mt][0], qf[nq][0], acc);
                acc = MFMA16(kf[mt][1], qf[nq][1], acc);
                s[mt][nq] = acc;
            }

        bool diag = (kt == qt);
        int kbase = kt * 64 + kh * 32 + quad * 4;
        int qbase = Q0 + qh * 32 + l15;
        #pragma unroll
        for (int mt = 0; mt < 2; mt++) {
            #pragma unroll
            for (int nq = 0; nq < 2; nq++) {
                short4v pk;
                #pragma unroll
                for (int rg = 0; rg < 4; rg++) {
                    float p = __builtin_amdgcn_exp2f(s[mt][nq][rg]);
                    if (diag && (kbase + mt * 16 + rg > qbase + nq * 16)) p = 0.f;
                    li[nq] += p;
                    pk[rg] = (short)f2b(p);
                }
                *(short4v*)&Pw[(nq * 16 + l15) * 40 + mt * 16 + quad * 4] = pk;
            }
        }
        bf16x8 pf[2];
        #pragma unroll
        for (int nq = 0; nq < 2; nq++)
            pf[nq] = *(const bf16x8*)&Pw[(nq * 16 + l15) * 40 + quad * 8];
        #pragma unroll
        for (int nq = 0; nq < 2; nq++)
            #pragma unroll
            for (int nh = 0; nh < 4; nh++)
                o[nq][nh] = MFMA16(pf[nq], vf[nh], o[nq][nh]);
    }

    // ---- epilogue: combine the two k'-halves ----
    __syncthreads();
    #pragma unroll
    for (int nq = 0; nq < 2; nq++) {
        li[nq] += __shfl_xor(li[nq], 16);
        li[nq] += __shfl_xor(li[nq], 32);
    }
    if (lane < 16) {
        Lbuf[w][lane]      = li[0];
        Lbuf[w][16 + lane] = li[1];
    }
    if (w == 1) {
        #pragma unroll
        for (int nq = 0; nq < 2; nq++)
            #pragma unroll
            for (int nh = 0; nh < 4; nh++)
                #pragma unroll
                for (int rg = 0; rg < 4; rg++)
                    Cbuf[nq * 16 + quad * 4 + rg][nh * 16 + l15] = o[nq][nh][rg];
    }
    __syncthreads();
    if (w == 0) {
        #pragma unroll
        for (int nq = 0; nq < 2; nq++) {
            #pragma unroll
            for (int rg = 0; rg < 4; rg++) {
                int qloc = nq * 16 + quad * 4 + rg;
                float lt = Lbuf[0][qloc] + Lbuf[1][qloc];
                float inv = 1.0f / lt;
                size_t row = (size_t)b * Tn + Q0 + qh * 32 + qloc;
                #pragma unroll
                for (int nh = 0; nh < 4; nh++) {
                    float val = o[nq][nh][rg] + Cbuf[qloc][nh * 16 + l15];
                    Out[row * Hn + nh * 16 + l15] = val * inv;
                }
            }
        }
    }
}

extern "C" void kernel_launch(void* const* d_in, const int* in_sizes, int n_in,
                              void* d_out, int out_size, void* d_ws, size_t ws_size,
                              hipStream_t stream) {
    const float* X  = (const float*)d_in[0];
    const float* Wq = (const float*)d_in[1];
    const float* Wk = (const float*)d_in[2];
    const float* Wv = (const float*)d_in[3];
    float* out = (float*)d_out;

    char* ws = (char*)d_ws;
    size_t szQ = (size_t)Bn * Tn * Hn * sizeof(unsigned short);  // 4 MiB
    unsigned short* Qp  = (unsigned short*)(ws);
    unsigned short* Kp  = (unsigned short*)(ws + szQ);
    unsigned short* VTp = (unsigned short*)(ws + 2 * szQ);
    unsigned short* WT  = (unsigned short*)(ws + 3 * szQ);   // + 48 KiB

    wtrans<<<3, 256, 0, stream>>>(Wq, Wk, Wv, WT);
    qkv<<<Bn * Tn / 64, 256, 0, stream>>>(X, WT, Qp, Kp, VTp);
    attn<<<1024, 128, 0, stream>>>(Qp, Kp, VTp, out);
}